// Round 5
// baseline (989.259 us; speedup 1.0000x reference)
//
#include <hip/hip_runtime.h>
#include <hip/hip_bf16.h>

typedef unsigned short u16;
typedef __bf16 bf16x8 __attribute__((ext_vector_type(8)));
typedef float  f32x4  __attribute__((ext_vector_type(4)));

__device__ __forceinline__ u16 f2bf(float f) {
    return __builtin_bit_cast(u16, (__bf16)f);
}
__device__ __forceinline__ f32x4 mfma16(bf16x8 a, bf16x8 b, f32x4 c) {
    return __builtin_amdgcn_mfma_f32_16x16x32_bf16(a, b, c, 0, 0, 0);
}
// async global->LDS, 16B per lane; LDS dest is wave-uniform base + lane*16
__device__ __forceinline__ void gl_lds16(const void* g, void* l) {
    __builtin_amdgcn_global_load_lds((const __attribute__((address_space(1))) void*)g,
                                     (__attribute__((address_space(3))) void*)l, 16, 0, 0);
}

// ---------------- elementwise f32 -> bf16 (4 elems/thread, exact grid) ----------------
__global__ void k_cast_bf16(const float* __restrict__ src, u16* __restrict__ dst) {
    long i = ((long)blockIdx.x * blockDim.x + threadIdx.x) * 4;
    float4 v = *(const float4*)(src + i);
    ushort4 o;
    o.x = f2bf(v.x); o.y = f2bf(v.y); o.z = f2bf(v.z); o.w = f2bf(v.w);
    *(ushort4*)(dst + i) = o;
}

// ---------------- f32 (K x N) -> bf16 transposed (N x K) ----------------
__global__ void k_transpose_cvt(const float* __restrict__ src, u16* __restrict__ dst,
                                int K, int N) {
    __shared__ float t[32][33];
    int n0 = blockIdx.x * 32, k0 = blockIdx.y * 32;
    int tx = threadIdx.x, ty = threadIdx.y;
    #pragma unroll
    for (int i = 0; i < 32; i += 8)
        t[ty + i][tx] = src[(long)(k0 + ty + i) * N + n0 + tx];
    __syncthreads();
    #pragma unroll
    for (int i = 0; i < 32; i += 8)
        dst[(long)(n0 + ty + i) * K + k0 + tx] = f2bf(t[tx][ty + i]);
}

// ---------------- float4 copy (past -> present) ----------------
__global__ void k_copy4(const float4* __restrict__ src, float4* __restrict__ dst) {
    long i = (long)blockIdx.x * blockDim.x + threadIdx.x;
    dst[i] = src[i];
}

// ================= 256-tile counted-vmcnt GEMM =================
// C(MxN,f32) = A(MxK,bf16) * Bt(NxK,bf16)^T.  BM=256, BN=64*BNF, BK=64.
// 512 threads = 8 waves (2M x 4N), per-wave C = 128 x 16*BNF.
// LDS: double-buffered A[256][64] + B[BN][64] bf16, rows 128B.
// Swizzle: logical 16B-chunk cc of row r stored at phys chunk cc^(r&7)
//   (written linearly by global_load_lds from a pre-swizzled global source;
//    ds_read applies the same XOR -> conflict-free fragment reads).
// Pipeline: stage tile kt+1 -> other buffer, s_waitcnt vmcnt(4+BNF) (tile kt
// landed, kt+1 in flight), barrier, compute 4 quadrant phases, barrier.
template<int BNF>
__global__ void __launch_bounds__(512, 2)
k_gemm8(const u16* __restrict__ A, const u16* __restrict__ Bt,
        float* __restrict__ C, int M, int N, int K, int gx)
{
    extern __shared__ u16 lds[];
    // XCD-aware bijective swizzle (nwg % 8 == 0 for all our grids)
    const int nwg = gridDim.x;
    const int bid = blockIdx.x;
    const int swzb = (bid & 7) * (nwg >> 3) + (bid >> 3);
    const long m0 = (long)(swzb / gx) * 256;
    const long n0 = (long)(swzb % gx) * (64 * BNF);

    const int t = threadIdx.x;
    const int l = t & 63;
    const int w = t >> 6;
    const int wm = w >> 2, wn = w & 3;

    // staging source (pre-swizzled): thread t writes phys chunk (r = t>>3 + 64k, pc = t&7)
    const int srow = t >> 3;
    const int scol = ((t & 7) ^ (srow & 7)) << 3;      // u16 col within 64-col tile row
    const u16* ap = A  + (m0 + srow) * (long)K + scol;
    const u16* bp = Bt + (n0 + srow) * (long)K + scol;
    const int sL = t * 8;                               // lds u16 offset (+4096 per k)

    // fragment read offsets (u16); row&7 == l&7 for all fragment rows
    const int swz0 = (((l >> 4) ^ (l & 7)) << 3);       // k-slice 0
    const int swz1 = ((((l >> 4) | 4) ^ (l & 7)) << 3); // k-slice 1
    const int arow = wm * 128 + (l & 15);
    const int aoff0 = arow * 64 + swz0, aoff1 = arow * 64 + swz1;
    const int brow = wn * (16 * BNF) + (l & 15);
    const int boff0 = brow * 64 + swz0, boff1 = brow * 64 + swz1;

    f32x4 acc[8][BNF];
    #pragma unroll
    for (int i = 0; i < 8; ++i)
        #pragma unroll
        for (int j = 0; j < BNF; ++j) acc[i][j] = (f32x4){0.f, 0.f, 0.f, 0.f};

    const int nt = K >> 6;
    // prologue: stage tile 0 -> buffer 0
    #pragma unroll
    for (int k = 0; k < 4; ++k)
        gl_lds16(ap + (long)k * 64 * K, &lds[sL + 4096 * k]);
    #pragma unroll
    for (int k = 0; k < BNF; ++k)
        gl_lds16(bp + (long)k * 64 * K, &lds[32768 + sL + 4096 * k]);

    for (int kt = 0; kt < nt; ++kt) {
        const int d = kt & 1;
        const int dA = d * 16384, dB = 32768 + d * 4096 * BNF;
        if (kt + 1 < nt) {
            const int e = d ^ 1;
            const u16* a1 = ap + (kt + 1) * 64;
            const u16* b1 = bp + (kt + 1) * 64;
            #pragma unroll
            for (int k = 0; k < 4; ++k)
                gl_lds16(a1 + (long)k * 64 * K, &lds[e * 16384 + sL + 4096 * k]);
            #pragma unroll
            for (int k = 0; k < BNF; ++k)
                gl_lds16(b1 + (long)k * 64 * K, &lds[32768 + e * 4096 * BNF + sL + 4096 * k]);
            if constexpr (BNF == 3) asm volatile("s_waitcnt vmcnt(7)" ::: "memory");
            else                    asm volatile("s_waitcnt vmcnt(8)" ::: "memory");
        } else {
            asm volatile("s_waitcnt vmcnt(0)" ::: "memory");
        }
        __builtin_amdgcn_sched_barrier(0);
        __builtin_amdgcn_s_barrier();          // (a) tile kt visible to all waves
        __builtin_amdgcn_sched_barrier(0);

        bf16x8 bfr[BNF][2];
        #pragma unroll
        for (int nf = 0; nf < BNF; ++nf) {
            bfr[nf][0] = *(const bf16x8*)&lds[dB + boff0 + nf * 1024];
            bfr[nf][1] = *(const bf16x8*)&lds[dB + boff1 + nf * 1024];
        }
        #pragma unroll
        for (int q = 0; q < 4; ++q) {
            bf16x8 af[2][2];
            #pragma unroll
            for (int mm = 0; mm < 2; ++mm) {
                af[mm][0] = *(const bf16x8*)&lds[dA + aoff0 + (q * 2 + mm) * 1024];
                af[mm][1] = *(const bf16x8*)&lds[dA + aoff1 + (q * 2 + mm) * 1024];
            }
            __builtin_amdgcn_s_setprio(1);
            #pragma unroll
            for (int mm = 0; mm < 2; ++mm)
                #pragma unroll
                for (int nf = 0; nf < BNF; ++nf) {
                    acc[q * 2 + mm][nf] = mfma16(af[mm][0], bfr[nf][0], acc[q * 2 + mm][nf]);
                    acc[q * 2 + mm][nf] = mfma16(af[mm][1], bfr[nf][1], acc[q * 2 + mm][nf]);
                }
            __builtin_amdgcn_s_setprio(0);
        }
        __builtin_amdgcn_sched_barrier(0);
        __builtin_amdgcn_s_barrier();          // (b) all reads done before next stage
        __builtin_amdgcn_sched_barrier(0);
    }

    // epilogue: C/D layout col = lane&15, row = (lane>>4)*4 + reg
    #pragma unroll
    for (int mf = 0; mf < 8; ++mf)
        #pragma unroll
        for (int nf = 0; nf < BNF; ++nf) {
            long row = m0 + wm * 128 + mf * 16 + ((l >> 4) << 2);
            float* cp = C + row * N + n0 + wn * (16 * BNF) + nf * 16 + (l & 15);
            #pragma unroll
            for (int r = 0; r < 4; ++r) cp[(long)r * N] = acc[mf][nf][r];
        }
}

// ---------------- RoPE + scatter ----------------
__global__ void k_rope_scatter(const float* __restrict__ qkv, const float* __restrict__ cosb,
                               const float* __restrict__ sinb, u16* __restrict__ Qb,
                               u16* __restrict__ Kb, u16* __restrict__ Vt,
                               float* __restrict__ present)
{
    long idx = (long)blockIdx.x * 256 + threadIdx.x;
    int pair = (int)(idx & 63);
    int rem  = (int)(idx >> 6);
    int slot = rem % 48;
    int tok  = rem / 48;
    int b = tok >> 11, s = tok & 2047;

    const float* base = qkv + (long)tok * 6144 + slot * 128;
    float x1 = base[pair], x2 = base[pair + 64];

    if (slot < 40) {
        float c  = cosb[s * 128 + pair];
        float sn = sinb[s * 128 + pair];
        float y1 = x1 * c - x2 * sn;
        float y2 = x2 * c + x1 * sn;
        if (slot < 32) {
            const float sc = 0.0883883476483184f;  // 1/sqrt(128), folded into Q
            long qoff = (((long)b * 32 + slot) * 2048 + s) * 128 + pair;
            Qb[qoff]      = f2bf(y1 * sc);
            Qb[qoff + 64] = f2bf(y2 * sc);
        } else {
            int kvh = slot - 32;
            long koff = (((long)b * 8 + kvh) * 2048 + s) * 128 + pair;
            Kb[koff]      = f2bf(y1);
            Kb[koff + 64] = f2bf(y2);
            long poff = ((((long)b * 2 + 0) * 8 + kvh) * 4096 + s) * 128 + pair;
            present[poff]      = y1;
            present[poff + 64] = y2;
        }
    } else {
        int kvh = slot - 40;
        long poff = ((((long)b * 2 + 1) * 8 + kvh) * 4096 + s) * 128 + pair;
        present[poff]      = x1;
        present[poff + 64] = x2;
        long voff = (((long)b * 8 + kvh) * 128 + pair) * 2048 + s;
        Vt[voff]             = f2bf(x1);
        Vt[voff + 64 * 2048] = f2bf(x2);
    }
}

// ---------------- causal GQA flash attention ----------------
// Block: 128 q-rows of one (b,h); 4 waves x 32 rows. Key tiles of 64, LDS-staged.
// LDS = 32 KB: Ks (16 KB, re-used as the per-wave P tiles after QK^T) + Vs (16 KB).
// qt is XOR-remapped per (h,b) so co-resident blocks have complementary causal depth.
__global__ void __launch_bounds__(256, 3)
k_attn(const u16* __restrict__ Qb, const u16* __restrict__ Kb,
       const u16* __restrict__ Vt, u16* __restrict__ attnB)
{
    __shared__ __align__(16) u16 Ks[64 * 128];   // [key][d] chunk16 swz; P alias after QK
    __shared__ __align__(16) u16 Vs[128 * 64];   // [d][key], chunk8 swz ^(row&7)
    const int l = threadIdx.x & 63;
    const int w = threadIdx.x >> 6;
    const int h = blockIdx.y, b = blockIdx.z;
    // work-balance: bijective qt remap so a CU's co-resident blocks mix depths
    const int qt = blockIdx.x ^ (((h >> 2) + 8 * b) & 15);
    const int kvh = h >> 2;
    const int q0 = qt * 128;
    u16* Psw = &Ks[w * 2048];                    // per-wave 32x64 P, aliases K tile

    const long qbase = (((long)b * 32 + h) * 2048 + q0 + w * 32) * 128;
    bf16x8 qf[2][4];
    #pragma unroll
    for (int mi = 0; mi < 2; ++mi)
        #pragma unroll
        for (int kk = 0; kk < 4; ++kk)
            qf[mi][kk] = *(const bf16x8*)(Qb + qbase + (long)(mi * 16 + (l & 15)) * 128
                                          + kk * 32 + ((l >> 4) << 3));

    f32x4 zero = {0.f, 0.f, 0.f, 0.f};
    f32x4 o[2][8];
    float mst[2][4], lst[2][4];
    #pragma unroll
    for (int mi = 0; mi < 2; ++mi) {
        #pragma unroll
        for (int j = 0; j < 8; ++j) o[mi][j] = zero;
        #pragma unroll
        for (int r = 0; r < 4; ++r) { mst[mi][r] = -3.0e38f; lst[mi][r] = 0.f; }
    }

    const long kbase = ((long)b * 8 + kvh) * (2048L * 128);
    const long vbase = ((long)b * 8 + kvh) * (128L * 2048);

    const int nkt = (q0 >> 6) + 2;  // keys 0 .. q0+127
    for (int kt = 0; kt < nkt; ++kt) {
        const int k0 = kt * 64;
        __syncthreads();  // all waves done with previous tile's Ks(P alias) + Vs
        #pragma unroll
        for (int i = 0; i < 4; ++i) {     // K tile: 16KB, 4 chunks/wave
            int c = w * 4 + i;
            int row = c * 4 + (l >> 4);
            int lg = ((l & 15) ^ (row & 15)) << 3;
            gl_lds16(Kb + kbase + (long)(k0 + row) * 128 + lg, &Ks[c * 512]);
        }
        #pragma unroll
        for (int i = 0; i < 4; ++i) {     // V^T tile: 16KB
            int c = w * 4 + i;
            int row = c * 8 + (l >> 3);
            int lg = ((l & 7) ^ (row & 7)) << 3;
            gl_lds16(Vt + vbase + (long)row * 2048 + k0 + lg, &Vs[c * 512]);
        }
        __syncthreads();  // staging complete

        // ---- S = Q K^T (16x16x32 MFMA, reduce over D=128) ----
        f32x4 s[2][4];
        #pragma unroll
        for (int mi = 0; mi < 2; ++mi)
            #pragma unroll
            for (int nf = 0; nf < 4; ++nf) s[mi][nf] = zero;
        #pragma unroll
        for (int kk = 0; kk < 4; ++kk) {
            bf16x8 kf[4];
            #pragma unroll
            for (int nf = 0; nf < 4; ++nf) {
                int row = nf * 16 + (l & 15);
                int ph = (kk * 4 + (l >> 4)) ^ (row & 15);
                kf[nf] = *(const bf16x8*)&Ks[row * 128 + ph * 8];
            }
            #pragma unroll
            for (int mi = 0; mi < 2; ++mi)
                #pragma unroll
                for (int nf = 0; nf < 4; ++nf)
                    s[mi][nf] = mfma16(qf[mi][kk], kf[nf], s[mi][nf]);
        }
        // ---- causal mask ----
        #pragma unroll
        for (int mi = 0; mi < 2; ++mi)
            #pragma unroll
            for (int nf = 0; nf < 4; ++nf)
                #pragma unroll
                for (int r = 0; r < 4; ++r) {
                    int rowg = q0 + w * 32 + mi * 16 + ((l >> 4) << 2) + r;
                    int colg = k0 + nf * 16 + (l & 15);
                    if (colg > rowg) s[mi][nf][r] = -1.0e30f;
                }
        // ---- online softmax (row reduce over 16-lane group) ----
        #pragma unroll
        for (int mi = 0; mi < 2; ++mi)
            #pragma unroll
            for (int r = 0; r < 4; ++r) {
                float t = fmaxf(fmaxf(s[mi][0][r], s[mi][1][r]),
                                fmaxf(s[mi][2][r], s[mi][3][r]));
                t = fmaxf(t, __shfl_xor(t, 1));
                t = fmaxf(t, __shfl_xor(t, 2));
                t = fmaxf(t, __shfl_xor(t, 4));
                t = fmaxf(t, __shfl_xor(t, 8));
                float nm = fmaxf(mst[mi][r], t);
                float sc = __expf(mst[mi][r] - nm);
                mst[mi][r] = nm;
                lst[mi][r] *= sc;
                #pragma unroll
                for (int nf2 = 0; nf2 < 8; ++nf2) o[mi][nf2][r] *= sc;
            }
        __syncthreads();  // all waves done READING Ks before P overwrites it
        // ---- P = exp(S - m) -> bf16 -> per-wave LDS (aliases Ks, swizzled) ----
        #pragma unroll
        for (int mi = 0; mi < 2; ++mi)
            #pragma unroll
            for (int nf = 0; nf < 4; ++nf)
                #pragma unroll
                for (int r = 0; r < 4; ++r) {
                    float p = __expf(s[mi][nf][r] - mst[mi][r]);
                    lst[mi][r] += p;
                    int row = mi * 16 + ((l >> 4) << 2) + r;
                    int col = nf * 16 + (l & 15);
                    Psw[row * 64 + (((col >> 3) ^ (row & 7)) << 3) + (col & 7)] = f2bf(p);
                }
        // ---- O += P V  (same-wave LDS write->read, lgkmcnt-ordered) ----
        #pragma unroll
        for (int kk2 = 0; kk2 < 2; ++kk2) {
            bf16x8 pa[2];
            #pragma unroll
            for (int mi = 0; mi < 2; ++mi) {
                int row = mi * 16 + (l & 15);
                int ph = (kk2 * 4 + (l >> 4)) ^ (row & 7);
                pa[mi] = *(const bf16x8*)&Psw[row * 64 + ph * 8];
            }
            #pragma unroll
            for (int nf2 = 0; nf2 < 8; ++nf2) {
                int vrow = nf2 * 16 + (l & 15);
                int ph = (kk2 * 4 + (l >> 4)) ^ (vrow & 7);
                bf16x8 vf = *(const bf16x8*)&Vs[vrow * 64 + ph * 8];
                #pragma unroll
                for (int mi = 0; mi < 2; ++mi)
                    o[mi][nf2] = mfma16(pa[mi], vf, o[mi][nf2]);
            }
        }
    }

    // ---- finalize: reduce row-sums, normalize, store bf16 ----
    #pragma unroll
    for (int mi = 0; mi < 2; ++mi)
        #pragma unroll
        for (int r = 0; r < 4; ++r) {
            float t = lst[mi][r];
            t += __shfl_xor(t, 1);
            t += __shfl_xor(t, 2);
            t += __shfl_xor(t, 4);
            t += __shfl_xor(t, 8);
            lst[mi][r] = 1.0f / t;
        }
    #pragma unroll
    for (int mi = 0; mi < 2; ++mi)
        #pragma unroll
        for (int nf2 = 0; nf2 < 8; ++nf2)
            #pragma unroll
            for (int r = 0; r < 4; ++r) {
                long row = (long)b * 2048 + q0 + w * 32 + mi * 16 + ((l >> 4) << 2) + r;
                attnB[row * 4096 + h * 128 + nf2 * 16 + (l & 15)] =
                    f2bf(o[mi][nf2][r] * lst[mi][r]);
            }
}

extern "C" void kernel_launch(void* const* d_in, const int* in_sizes, int n_in,
                              void* d_out, int out_size, void* d_ws, size_t ws_size,
                              hipStream_t stream)
{
    (void)in_sizes; (void)n_in; (void)out_size; (void)ws_size;
    const float* hidden = (const float*)d_in[0];
    const float* past   = (const float*)d_in[1];
    const float* cosb   = (const float*)d_in[2];
    const float* sinb   = (const float*)d_in[3];
    const float* Wq     = (const float*)d_in[4];
    const float* Wk     = (const float*)d_in[5];
    const float* Wv     = (const float*)d_in[6];
    const float* Wo     = (const float*)d_in[7];
    float* out     = (float*)d_out;             // (B,S,HID) f32
    float* present = out + 16777216L;           // (B,2,KVH,MAXPOS,D) f32

    // workspace layout (total 224 MB)
    char* ws = (char*)d_ws;
    u16*  hiddenB = (u16*)(ws);                  // 33,554,432 B (later aliased as Qbuf)
    u16*  WqkvT   = (u16*)(ws + 33554432L);      // 50,331,648 B  (6144 x 4096 bf16)
    u16*  WoT     = (u16*)(ws + 83886080L);      // 33,554,432 B
    float* QKVf   = (float*)(ws + 117440512L);   // 100,663,296 B (later aliased as attnB)
    u16*  Kb      = (u16*)(ws + 218103808L);     // 8,388,608 B
    u16*  Vt      = (u16*)(ws + 226492416L);     // 8,388,608 B
    u16*  Qbuf    = hiddenB;                     // reuse after QKV GEMM consumed hiddenB
    u16*  attnB   = (u16*)QKVf;                  // reuse after rope consumed QKVf

    static bool attr_done = false;
    if (!attr_done) {
        hipFuncSetAttribute((const void*)k_gemm8<3>,
                            hipFuncAttributeMaxDynamicSharedMemorySize, 114688);
        hipFuncSetAttribute((const void*)k_gemm8<4>,
                            hipFuncAttributeMaxDynamicSharedMemorySize, 131072);
        attr_done = true;
    }

    k_cast_bf16<<<16384, 256, 0, stream>>>(hidden, hiddenB);
    dim3 tb(32, 8);
    k_transpose_cvt<<<dim3(128, 128), tb, 0, stream>>>(Wq, WqkvT, 4096, 4096);
    k_transpose_cvt<<<dim3(32, 128),  tb, 0, stream>>>(Wk, WqkvT + 4096L * 4096, 4096, 1024);
    k_transpose_cvt<<<dim3(32, 128),  tb, 0, stream>>>(Wv, WqkvT + 5120L * 4096, 4096, 1024);
    k_transpose_cvt<<<dim3(128, 128), tb, 0, stream>>>(Wo, WoT, 4096, 4096);
    k_copy4<<<16384, 256, 0, stream>>>((const float4*)past, (float4*)present);
    // QKV: M=4096, N=6144, tiles 256x192 -> grid 16x32 = 512 (2.0 CU-rounds)
    k_gemm8<3><<<512, 512, 114688, stream>>>(hiddenB, WqkvT, QKVf, 4096, 6144, 4096, 32);
    k_rope_scatter<<<49152, 256, 0, stream>>>(QKVf, cosb, sinb, Qbuf, Kb, Vt, present);
    k_attn<<<dim3(16, 32, 2), 256, 0, stream>>>(Qbuf, Kb, Vt, attnB);
    // Wo: M=N=4096, tiles 256x256 -> grid 16x16 = 256 (1.0 CU-rounds)
    k_gemm8<4><<<256, 512, 131072, stream>>>(attnB, WoT, out, 4096, 4096, 4096, 16);
}

// Round 6
// 717.058 us; speedup vs baseline: 1.3796x; 1.3796x over previous
//
#include <hip/hip_runtime.h>
#include <hip/hip_bf16.h>

typedef unsigned short u16;
typedef __bf16 bf16x8 __attribute__((ext_vector_type(8)));
typedef float  f32x4  __attribute__((ext_vector_type(4)));

__device__ __forceinline__ u16 f2bf(float f) {
    return __builtin_bit_cast(u16, (__bf16)f);
}
__device__ __forceinline__ f32x4 mfma16(bf16x8 a, bf16x8 b, f32x4 c) {
    return __builtin_amdgcn_mfma_f32_16x16x32_bf16(a, b, c, 0, 0, 0);
}
// async global->LDS, 16B per lane; LDS dest is wave-uniform base + lane*16
__device__ __forceinline__ void gl_lds16(const void* g, void* l) {
    __builtin_amdgcn_global_load_lds((const __attribute__((address_space(1))) void*)g,
                                     (__attribute__((address_space(3))) void*)l, 16, 0, 0);
}

// ---------------- elementwise f32 -> bf16 (4 elems/thread, exact grid) ----------------
__global__ void k_cast_bf16(const float* __restrict__ src, u16* __restrict__ dst) {
    long i = ((long)blockIdx.x * blockDim.x + threadIdx.x) * 4;
    float4 v = *(const float4*)(src + i);
    ushort4 o;
    o.x = f2bf(v.x); o.y = f2bf(v.y); o.z = f2bf(v.z); o.w = f2bf(v.w);
    *(ushort4*)(dst + i) = o;
}

// ---------------- f32 (K x N) -> bf16 transposed (N x K) ----------------
__global__ void k_transpose_cvt(const float* __restrict__ src, u16* __restrict__ dst,
                                int K, int N) {
    __shared__ float t[32][33];
    int n0 = blockIdx.x * 32, k0 = blockIdx.y * 32;
    int tx = threadIdx.x, ty = threadIdx.y;
    #pragma unroll
    for (int i = 0; i < 32; i += 8)
        t[ty + i][tx] = src[(long)(k0 + ty + i) * N + n0 + tx];
    __syncthreads();
    #pragma unroll
    for (int i = 0; i < 32; i += 8)
        dst[(long)(n0 + ty + i) * K + k0 + tx] = f2bf(t[tx][ty + i]);
}

// ---------------- float4 copy (past -> present) ----------------
__global__ void k_copy4(const float4* __restrict__ src, float4* __restrict__ dst) {
    long i = (long)blockIdx.x * blockDim.x + threadIdx.x;
    dst[i] = src[i];
}

// ================= 256-tile counted-vmcnt GEMM =================
// C(MxN,f32) = A(MxK,bf16) * Bt(NxK,bf16)^T.  BM=256, BN=64*BNF, BK=64.
// 512 threads = 8 waves (2M x 4N), per-wave C = 128 x 16*BNF.
// LDS: double-buffered A[256][64] + B[BN][64] bf16, rows 128B.
// Swizzle: logical 16B-chunk cc of row r stored at phys chunk cc^(r&7)
//   (written linearly by global_load_lds from a pre-swizzled global source;
//    ds_read applies the same XOR -> conflict-free fragment reads).
// Pipeline: stage tile kt+1 -> other buffer, s_waitcnt vmcnt(4+BNF) (tile kt
// landed, kt+1 in flight), barrier, compute 4 quadrant phases, barrier.
template<int BNF>
__global__ void __launch_bounds__(512, 2)
k_gemm8(const u16* __restrict__ A, const u16* __restrict__ Bt,
        float* __restrict__ C, int M, int N, int K, int gx)
{
    extern __shared__ u16 lds[];
    // XCD-aware bijective swizzle (nwg % 8 == 0 for all our grids)
    const int nwg = gridDim.x;
    const int bid = blockIdx.x;
    const int swzb = (bid & 7) * (nwg >> 3) + (bid >> 3);
    const long m0 = (long)(swzb / gx) * 256;
    const long n0 = (long)(swzb % gx) * (64 * BNF);

    const int t = threadIdx.x;
    const int l = t & 63;
    const int w = t >> 6;
    const int wm = w >> 2, wn = w & 3;

    // staging source (pre-swizzled): thread t writes phys chunk (r = t>>3 + 64k, pc = t&7)
    const int srow = t >> 3;
    const int scol = ((t & 7) ^ (srow & 7)) << 3;      // u16 col within 64-col tile row
    const u16* ap = A  + (m0 + srow) * (long)K + scol;
    const u16* bp = Bt + (n0 + srow) * (long)K + scol;
    const int sL = t * 8;                               // lds u16 offset (+4096 per k)

    // fragment read offsets (u16); row&7 == l&7 for all fragment rows
    const int swz0 = (((l >> 4) ^ (l & 7)) << 3);       // k-slice 0
    const int swz1 = ((((l >> 4) | 4) ^ (l & 7)) << 3); // k-slice 1
    const int arow = wm * 128 + (l & 15);
    const int aoff0 = arow * 64 + swz0, aoff1 = arow * 64 + swz1;
    const int brow = wn * (16 * BNF) + (l & 15);
    const int boff0 = brow * 64 + swz0, boff1 = brow * 64 + swz1;

    f32x4 acc[8][BNF];
    #pragma unroll
    for (int i = 0; i < 8; ++i)
        #pragma unroll
        for (int j = 0; j < BNF; ++j) acc[i][j] = (f32x4){0.f, 0.f, 0.f, 0.f};

    const int nt = K >> 6;
    // prologue: stage tile 0 -> buffer 0
    #pragma unroll
    for (int k = 0; k < 4; ++k)
        gl_lds16(ap + (long)k * 64 * K, &lds[sL + 4096 * k]);
    #pragma unroll
    for (int k = 0; k < BNF; ++k)
        gl_lds16(bp + (long)k * 64 * K, &lds[32768 + sL + 4096 * k]);

    for (int kt = 0; kt < nt; ++kt) {
        const int d = kt & 1;
        const int dA = d * 16384, dB = 32768 + d * 4096 * BNF;
        if (kt + 1 < nt) {
            const int e = d ^ 1;
            const u16* a1 = ap + (kt + 1) * 64;
            const u16* b1 = bp + (kt + 1) * 64;
            #pragma unroll
            for (int k = 0; k < 4; ++k)
                gl_lds16(a1 + (long)k * 64 * K, &lds[e * 16384 + sL + 4096 * k]);
            #pragma unroll
            for (int k = 0; k < BNF; ++k)
                gl_lds16(b1 + (long)k * 64 * K, &lds[32768 + e * 4096 * BNF + sL + 4096 * k]);
            if constexpr (BNF == 3) asm volatile("s_waitcnt vmcnt(7)" ::: "memory");
            else                    asm volatile("s_waitcnt vmcnt(8)" ::: "memory");
        } else {
            asm volatile("s_waitcnt vmcnt(0)" ::: "memory");
        }
        __builtin_amdgcn_sched_barrier(0);
        __builtin_amdgcn_s_barrier();          // (a) tile kt visible to all waves
        __builtin_amdgcn_sched_barrier(0);

        bf16x8 bfr[BNF][2];
        #pragma unroll
        for (int nf = 0; nf < BNF; ++nf) {
            bfr[nf][0] = *(const bf16x8*)&lds[dB + boff0 + nf * 1024];
            bfr[nf][1] = *(const bf16x8*)&lds[dB + boff1 + nf * 1024];
        }
        #pragma unroll
        for (int q = 0; q < 4; ++q) {
            bf16x8 af[2][2];
            #pragma unroll
            for (int mm = 0; mm < 2; ++mm) {
                af[mm][0] = *(const bf16x8*)&lds[dA + aoff0 + (q * 2 + mm) * 1024];
                af[mm][1] = *(const bf16x8*)&lds[dA + aoff1 + (q * 2 + mm) * 1024];
            }
            __builtin_amdgcn_s_setprio(1);
            #pragma unroll
            for (int mm = 0; mm < 2; ++mm)
                #pragma unroll
                for (int nf = 0; nf < BNF; ++nf) {
                    acc[q * 2 + mm][nf] = mfma16(af[mm][0], bfr[nf][0], acc[q * 2 + mm][nf]);
                    acc[q * 2 + mm][nf] = mfma16(af[mm][1], bfr[nf][1], acc[q * 2 + mm][nf]);
                }
            __builtin_amdgcn_s_setprio(0);
        }
        __builtin_amdgcn_sched_barrier(0);
        __builtin_amdgcn_s_barrier();          // (b) all reads done before next stage
        __builtin_amdgcn_sched_barrier(0);
    }

    // epilogue: C/D layout col = lane&15, row = (lane>>4)*4 + reg
    #pragma unroll
    for (int mf = 0; mf < 8; ++mf)
        #pragma unroll
        for (int nf = 0; nf < BNF; ++nf) {
            long row = m0 + wm * 128 + mf * 16 + ((l >> 4) << 2);
            float* cp = C + row * N + n0 + wn * (16 * BNF) + nf * 16 + (l & 15);
            #pragma unroll
            for (int r = 0; r < 4; ++r) cp[(long)r * N] = acc[mf][nf][r];
        }
}

// ---------------- RoPE + scatter ----------------
__global__ void k_rope_scatter(const float* __restrict__ qkv, const float* __restrict__ cosb,
                               const float* __restrict__ sinb, u16* __restrict__ Qb,
                               u16* __restrict__ Kb, u16* __restrict__ Vt,
                               float* __restrict__ present)
{
    long idx = (long)blockIdx.x * 256 + threadIdx.x;
    int pair = (int)(idx & 63);
    int rem  = (int)(idx >> 6);
    int slot = rem % 48;
    int tok  = rem / 48;
    int b = tok >> 11, s = tok & 2047;

    const float* base = qkv + (long)tok * 6144 + slot * 128;
    float x1 = base[pair], x2 = base[pair + 64];

    if (slot < 40) {
        float c  = cosb[s * 128 + pair];
        float sn = sinb[s * 128 + pair];
        float y1 = x1 * c - x2 * sn;
        float y2 = x2 * c + x1 * sn;
        if (slot < 32) {
            const float sc = 0.0883883476483184f;  // 1/sqrt(128), folded into Q
            long qoff = (((long)b * 32 + slot) * 2048 + s) * 128 + pair;
            Qb[qoff]      = f2bf(y1 * sc);
            Qb[qoff + 64] = f2bf(y2 * sc);
        } else {
            int kvh = slot - 32;
            long koff = (((long)b * 8 + kvh) * 2048 + s) * 128 + pair;
            Kb[koff]      = f2bf(y1);
            Kb[koff + 64] = f2bf(y2);
            long poff = ((((long)b * 2 + 0) * 8 + kvh) * 4096 + s) * 128 + pair;
            present[poff]      = y1;
            present[poff + 64] = y2;
        }
    } else {
        int kvh = slot - 40;
        long poff = ((((long)b * 2 + 1) * 8 + kvh) * 4096 + s) * 128 + pair;
        present[poff]      = x1;
        present[poff + 64] = x2;
        long voff = (((long)b * 8 + kvh) * 128 + pair) * 2048 + s;
        Vt[voff]             = f2bf(x1);
        Vt[voff + 64 * 2048] = f2bf(x2);
    }
}

// ---------------- causal GQA flash attention ----------------
// Block: 128 q-rows of one (b,h); 4 waves x 32 rows. Key tiles of 64, LDS-staged.
// LDS = 32 KB: Ks (16 KB, re-used as the per-wave P tiles after QK^T) + Vs (16 KB).
// qt is XOR-remapped per (h,b) so co-resident blocks have complementary causal depth.
// NOTE: launch_bounds must stay (256,2) — (256,3) caps VGPR at ~84 and spills
// the o/s/qf register working set (~200 regs) to scratch: R5 showed FETCH
// 70->715 MB and 2x duration. VGPR=128 @ (256,2) + 32KB LDS = 4 blocks/CU.
__global__ void __launch_bounds__(256, 2)
k_attn(const u16* __restrict__ Qb, const u16* __restrict__ Kb,
       const u16* __restrict__ Vt, u16* __restrict__ attnB)
{
    __shared__ __align__(16) u16 Ks[64 * 128];   // [key][d] chunk16 swz; P alias after QK
    __shared__ __align__(16) u16 Vs[128 * 64];   // [d][key], chunk8 swz ^(row&7)
    const int l = threadIdx.x & 63;
    const int w = threadIdx.x >> 6;
    const int h = blockIdx.y, b = blockIdx.z;
    // work-balance: bijective qt remap so a CU's co-resident blocks mix depths
    const int qt = blockIdx.x ^ (((h >> 2) + 8 * b) & 15);
    const int kvh = h >> 2;
    const int q0 = qt * 128;
    u16* Psw = &Ks[w * 2048];                    // per-wave 32x64 P, aliases K tile

    const long qbase = (((long)b * 32 + h) * 2048 + q0 + w * 32) * 128;
    bf16x8 qf[2][4];
    #pragma unroll
    for (int mi = 0; mi < 2; ++mi)
        #pragma unroll
        for (int kk = 0; kk < 4; ++kk)
            qf[mi][kk] = *(const bf16x8*)(Qb + qbase + (long)(mi * 16 + (l & 15)) * 128
                                          + kk * 32 + ((l >> 4) << 3));

    f32x4 zero = {0.f, 0.f, 0.f, 0.f};
    f32x4 o[2][8];
    float mst[2][4], lst[2][4];
    #pragma unroll
    for (int mi = 0; mi < 2; ++mi) {
        #pragma unroll
        for (int j = 0; j < 8; ++j) o[mi][j] = zero;
        #pragma unroll
        for (int r = 0; r < 4; ++r) { mst[mi][r] = -3.0e38f; lst[mi][r] = 0.f; }
    }

    const long kbase = ((long)b * 8 + kvh) * (2048L * 128);
    const long vbase = ((long)b * 8 + kvh) * (128L * 2048);

    const int nkt = (q0 >> 6) + 2;  // keys 0 .. q0+127
    for (int kt = 0; kt < nkt; ++kt) {
        const int k0 = kt * 64;
        __syncthreads();  // all waves done with previous tile's Ks(P alias) + Vs
        #pragma unroll
        for (int i = 0; i < 4; ++i) {     // K tile: 16KB, 4 chunks/wave
            int c = w * 4 + i;
            int row = c * 4 + (l >> 4);
            int lg = ((l & 15) ^ (row & 15)) << 3;
            gl_lds16(Kb + kbase + (long)(k0 + row) * 128 + lg, &Ks[c * 512]);
        }
        #pragma unroll
        for (int i = 0; i < 4; ++i) {     // V^T tile: 16KB
            int c = w * 4 + i;
            int row = c * 8 + (l >> 3);
            int lg = ((l & 7) ^ (row & 7)) << 3;
            gl_lds16(Vt + vbase + (long)row * 2048 + k0 + lg, &Vs[c * 512]);
        }
        __syncthreads();  // staging complete

        // ---- S = Q K^T (16x16x32 MFMA, reduce over D=128) ----
        f32x4 s[2][4];
        #pragma unroll
        for (int mi = 0; mi < 2; ++mi)
            #pragma unroll
            for (int nf = 0; nf < 4; ++nf) s[mi][nf] = zero;
        #pragma unroll
        for (int kk = 0; kk < 4; ++kk) {
            bf16x8 kf[4];
            #pragma unroll
            for (int nf = 0; nf < 4; ++nf) {
                int row = nf * 16 + (l & 15);
                int ph = (kk * 4 + (l >> 4)) ^ (row & 15);
                kf[nf] = *(const bf16x8*)&Ks[row * 128 + ph * 8];
            }
            #pragma unroll
            for (int mi = 0; mi < 2; ++mi)
                #pragma unroll
                for (int nf = 0; nf < 4; ++nf)
                    s[mi][nf] = mfma16(qf[mi][kk], kf[nf], s[mi][nf]);
        }
        // ---- causal mask ----
        #pragma unroll
        for (int mi = 0; mi < 2; ++mi)
            #pragma unroll
            for (int nf = 0; nf < 4; ++nf)
                #pragma unroll
                for (int r = 0; r < 4; ++r) {
                    int rowg = q0 + w * 32 + mi * 16 + ((l >> 4) << 2) + r;
                    int colg = k0 + nf * 16 + (l & 15);
                    if (colg > rowg) s[mi][nf][r] = -1.0e30f;
                }
        // ---- online softmax (row reduce over 16-lane group) ----
        #pragma unroll
        for (int mi = 0; mi < 2; ++mi)
            #pragma unroll
            for (int r = 0; r < 4; ++r) {
                float t = fmaxf(fmaxf(s[mi][0][r], s[mi][1][r]),
                                fmaxf(s[mi][2][r], s[mi][3][r]));
                t = fmaxf(t, __shfl_xor(t, 1));
                t = fmaxf(t, __shfl_xor(t, 2));
                t = fmaxf(t, __shfl_xor(t, 4));
                t = fmaxf(t, __shfl_xor(t, 8));
                float nm = fmaxf(mst[mi][r], t);
                float sc = __expf(mst[mi][r] - nm);
                mst[mi][r] = nm;
                lst[mi][r] *= sc;
                #pragma unroll
                for (int nf2 = 0; nf2 < 8; ++nf2) o[mi][nf2][r] *= sc;
            }
        __syncthreads();  // all waves done READING Ks before P overwrites it
        // ---- P = exp(S - m) -> bf16 -> per-wave LDS (aliases Ks, swizzled) ----
        #pragma unroll
        for (int mi = 0; mi < 2; ++mi)
            #pragma unroll
            for (int nf = 0; nf < 4; ++nf)
                #pragma unroll
                for (int r = 0; r < 4; ++r) {
                    float p = __expf(s[mi][nf][r] - mst[mi][r]);
                    lst[mi][r] += p;
                    int row = mi * 16 + ((l >> 4) << 2) + r;
                    int col = nf * 16 + (l & 15);
                    Psw[row * 64 + (((col >> 3) ^ (row & 7)) << 3) + (col & 7)] = f2bf(p);
                }
        // ---- O += P V  (same-wave LDS write->read, lgkmcnt-ordered) ----
        #pragma unroll
        for (int kk2 = 0; kk2 < 2; ++kk2) {
            bf16x8 pa[2];
            #pragma unroll
            for (int mi = 0; mi < 2; ++mi) {
                int row = mi * 16 + (l & 15);
                int ph = (kk2 * 4 + (l >> 4)) ^ (row & 7);
                pa[mi] = *(const bf16x8*)&Psw[row * 64 + ph * 8];
            }
            #pragma unroll
            for (int nf2 = 0; nf2 < 8; ++nf2) {
                int vrow = nf2 * 16 + (l & 15);
                int ph = (kk2 * 4 + (l >> 4)) ^ (vrow & 7);
                bf16x8 vf = *(const bf16x8*)&Vs[vrow * 64 + ph * 8];
                #pragma unroll
                for (int mi = 0; mi < 2; ++mi)
                    o[mi][nf2] = mfma16(pa[mi], vf, o[mi][nf2]);
            }
        }
    }

    // ---- finalize: reduce row-sums, normalize, store bf16 ----
    #pragma unroll
    for (int mi = 0; mi < 2; ++mi)
        #pragma unroll
        for (int r = 0; r < 4; ++r) {
            float t = lst[mi][r];
            t += __shfl_xor(t, 1);
            t += __shfl_xor(t, 2);
            t += __shfl_xor(t, 4);
            t += __shfl_xor(t, 8);
            lst[mi][r] = 1.0f / t;
        }
    #pragma unroll
    for (int mi = 0; mi < 2; ++mi)
        #pragma unroll
        for (int nf2 = 0; nf2 < 8; ++nf2)
            #pragma unroll
            for (int r = 0; r < 4; ++r) {
                long row = (long)b * 2048 + q0 + w * 32 + mi * 16 + ((l >> 4) << 2) + r;
                attnB[row * 4096 + h * 128 + nf2 * 16 + (l & 15)] =
                    f2bf(o[mi][nf2][r] * lst[mi][r]);
            }
}

extern "C" void kernel_launch(void* const* d_in, const int* in_sizes, int n_in,
                              void* d_out, int out_size, void* d_ws, size_t ws_size,
                              hipStream_t stream)
{
    (void)in_sizes; (void)n_in; (void)out_size; (void)ws_size;
    const float* hidden = (const float*)d_in[0];
    const float* past   = (const float*)d_in[1];
    const float* cosb   = (const float*)d_in[2];
    const float* sinb   = (const float*)d_in[3];
    const float* Wq     = (const float*)d_in[4];
    const float* Wk     = (const float*)d_in[5];
    const float* Wv     = (const float*)d_in[6];
    const float* Wo     = (const float*)d_in[7];
    float* out     = (float*)d_out;             // (B,S,HID) f32
    float* present = out + 16777216L;           // (B,2,KVH,MAXPOS,D) f32

    // workspace layout (total 224 MB)
    char* ws = (char*)d_ws;
    u16*  hiddenB = (u16*)(ws);                  // 33,554,432 B (later aliased as Qbuf)
    u16*  WqkvT   = (u16*)(ws + 33554432L);      // 50,331,648 B  (6144 x 4096 bf16)
    u16*  WoT     = (u16*)(ws + 83886080L);      // 33,554,432 B
    float* QKVf   = (float*)(ws + 117440512L);   // 100,663,296 B (later aliased as attnB)
    u16*  Kb      = (u16*)(ws + 218103808L);     // 8,388,608 B
    u16*  Vt      = (u16*)(ws + 226492416L);     // 8,388,608 B
    u16*  Qbuf    = hiddenB;                     // reuse after QKV GEMM consumed hiddenB
    u16*  attnB   = (u16*)QKVf;                  // reuse after rope consumed QKVf

    static bool attr_done = false;
    if (!attr_done) {
        hipFuncSetAttribute((const void*)k_gemm8<3>,
                            hipFuncAttributeMaxDynamicSharedMemorySize, 114688);
        hipFuncSetAttribute((const void*)k_gemm8<4>,
                            hipFuncAttributeMaxDynamicSharedMemorySize, 131072);
        attr_done = true;
    }

    k_cast_bf16<<<16384, 256, 0, stream>>>(hidden, hiddenB);
    dim3 tb(32, 8);
    k_transpose_cvt<<<dim3(128, 128), tb, 0, stream>>>(Wq, WqkvT, 4096, 4096);
    k_transpose_cvt<<<dim3(32, 128),  tb, 0, stream>>>(Wk, WqkvT + 4096L * 4096, 4096, 1024);
    k_transpose_cvt<<<dim3(32, 128),  tb, 0, stream>>>(Wv, WqkvT + 5120L * 4096, 4096, 1024);
    k_transpose_cvt<<<dim3(128, 128), tb, 0, stream>>>(Wo, WoT, 4096, 4096);
    k_copy4<<<16384, 256, 0, stream>>>((const float4*)past, (float4*)present);
    // QKV: M=4096, N=6144, tiles 256x192 -> grid 16x32 = 512 (2.0 CU-rounds)
    k_gemm8<3><<<512, 512, 114688, stream>>>(hiddenB, WqkvT, QKVf, 4096, 6144, 4096, 32);
    k_rope_scatter<<<49152, 256, 0, stream>>>(QKVf, cosb, sinb, Qbuf, Kb, Vt, present);
    k_attn<<<dim3(16, 32, 2), 256, 0, stream>>>(Qbuf, Kb, Vt, attnB);
    // Wo: M=N=4096, tiles 256x256 -> grid 16x16 = 256 (1.0 CU-rounds)
    k_gemm8<4><<<256, 512, 131072, stream>>>(attnB, WoT, out, 4096, 4096, 4096, 16);
}

// Round 7
// 692.335 us; speedup vs baseline: 1.4289x; 1.0357x over previous
//
#include <hip/hip_runtime.h>
#include <hip/hip_bf16.h>

typedef unsigned short u16;
typedef __bf16 bf16x8 __attribute__((ext_vector_type(8)));
typedef float  f32x4  __attribute__((ext_vector_type(4)));

__device__ __forceinline__ u16 f2bf(float f) {
    return __builtin_bit_cast(u16, (__bf16)f);
}
__device__ __forceinline__ f32x4 mfma16(bf16x8 a, bf16x8 b, f32x4 c) {
    return __builtin_amdgcn_mfma_f32_16x16x32_bf16(a, b, c, 0, 0, 0);
}
// async global->LDS, 16B per lane; LDS dest is wave-uniform base + lane*16
__device__ __forceinline__ void gl_lds16(const void* g, void* l) {
    __builtin_amdgcn_global_load_lds((const __attribute__((address_space(1))) void*)g,
                                     (__attribute__((address_space(3))) void*)l, 16, 0, 0);
}

// ---------------- elementwise f32 -> bf16 (4 elems/thread, exact grid) ----------------
__global__ void k_cast_bf16(const float* __restrict__ src, u16* __restrict__ dst) {
    long i = ((long)blockIdx.x * blockDim.x + threadIdx.x) * 4;
    float4 v = *(const float4*)(src + i);
    ushort4 o;
    o.x = f2bf(v.x); o.y = f2bf(v.y); o.z = f2bf(v.z); o.w = f2bf(v.w);
    *(ushort4*)(dst + i) = o;
}

// ---------------- f32 (K x N) -> bf16 transposed (N x K) ----------------
__global__ void k_transpose_cvt(const float* __restrict__ src, u16* __restrict__ dst,
                                int K, int N) {
    __shared__ float t[32][33];
    int n0 = blockIdx.x * 32, k0 = blockIdx.y * 32;
    int tx = threadIdx.x, ty = threadIdx.y;
    #pragma unroll
    for (int i = 0; i < 32; i += 8)
        t[ty + i][tx] = src[(long)(k0 + ty + i) * N + n0 + tx];
    __syncthreads();
    #pragma unroll
    for (int i = 0; i < 32; i += 8)
        dst[(long)(n0 + ty + i) * K + k0 + tx] = f2bf(t[tx][ty + i]);
}

// ---------------- copy only rows s in [2048,4096) of past -> present ----------------
// rope_scatter writes rows [0,2048) of every (b, k/v, kvh) plane; only the tail
// needs the past-cache copy. Each plane is 4096*128 f32 = 131072 float4;
// second half starts at +65536.
__global__ void k_copy_half(const float4* __restrict__ src, float4* __restrict__ dst) {
    long i = (long)blockIdx.x * 256 + threadIdx.x;   // 0 .. 2^21-1
    long g = i >> 16;                                // plane index (32 planes)
    long inner = i & 65535;
    long off = g * 131072 + 65536 + inner;
    dst[off] = src[off];
}

// ================= 256-tile counted-vmcnt GEMM, 4-phase interleave =================
// C(MxN,f32) = A(MxK,bf16) * Bt(NxK,bf16)^T.  BM=256, BN=64*BNF, BK=64.
// 512 threads = 8 waves (2M x 4N), per-wave C = 128 x 16*BNF.
// LDS: double-buffered A[256][64] + B[BN][64] bf16, rows 128B.
// Swizzle: logical 16B-chunk cc of row r stored at phys chunk cc^(r&7)
//   (written linearly by global_load_lds from a pre-swizzled global source;
//    ds_read applies the same XOR -> conflict-free fragment reads).
// Schedule per K-tile: issue next tile's 4+BNF loads -> vmcnt(4+BNF) (counted:
// current tile landed, next in flight) -> barrier -> 4 quadrant phases, each
// {ds_read af[q] | barrier | lgkmcnt(0) | setprio(1) MFMAx(4*BNF) setprio(0)}
// -> trailing barrier (protects buffer d from next tile's overwriting loads).
template<int BNF>
__global__ void __launch_bounds__(512, 2)
k_gemm8(const u16* __restrict__ A, const u16* __restrict__ Bt,
        float* __restrict__ C, int M, int N, int K, int gx)
{
    extern __shared__ u16 lds[];
    // XCD-aware bijective swizzle (nwg % 8 == 0 for all our grids)
    const int nwg = gridDim.x;
    const int bid = blockIdx.x;
    const int swzb = (bid & 7) * (nwg >> 3) + (bid >> 3);
    const long m0 = (long)(swzb / gx) * 256;
    const long n0 = (long)(swzb % gx) * (64 * BNF);

    const int t = threadIdx.x;
    const int l = t & 63;
    const int w = t >> 6;
    const int wm = w >> 2, wn = w & 3;

    // staging source (pre-swizzled): thread t writes phys chunk (r = t>>3 + 64k, pc = t&7)
    const int srow = t >> 3;
    const int scol = ((t & 7) ^ (srow & 7)) << 3;      // u16 col within 64-col tile row
    const u16* ap = A  + (m0 + srow) * (long)K + scol;
    const u16* bp = Bt + (n0 + srow) * (long)K + scol;
    const int sL = t * 8;                               // lds u16 offset (+4096 per k)

    // fragment read offsets (u16); row&7 == l&7 for all fragment rows
    const int swz0 = (((l >> 4) ^ (l & 7)) << 3);       // k-slice 0
    const int swz1 = ((((l >> 4) | 4) ^ (l & 7)) << 3); // k-slice 1
    const int arow = wm * 128 + (l & 15);
    const int aoff0 = arow * 64 + swz0, aoff1 = arow * 64 + swz1;
    const int brow = wn * (16 * BNF) + (l & 15);
    const int boff0 = brow * 64 + swz0, boff1 = brow * 64 + swz1;

    f32x4 acc[8][BNF];
    #pragma unroll
    for (int i = 0; i < 8; ++i)
        #pragma unroll
        for (int j = 0; j < BNF; ++j) acc[i][j] = (f32x4){0.f, 0.f, 0.f, 0.f};

    const int nt = K >> 6;
    // prologue: stage tile 0 -> buffer 0
    #pragma unroll
    for (int k = 0; k < 4; ++k)
        gl_lds16(ap + (long)k * 64 * K, &lds[sL + 4096 * k]);
    #pragma unroll
    for (int k = 0; k < BNF; ++k)
        gl_lds16(bp + (long)k * 64 * K, &lds[32768 + sL + 4096 * k]);

    for (int kt = 0; kt < nt; ++kt) {
        const int d = kt & 1;
        const int dA = d * 16384, dB = 32768 + d * 4096 * BNF;
        if (kt + 1 < nt) {
            const int e = d ^ 1;
            const u16* a1 = ap + (kt + 1) * 64;
            const u16* b1 = bp + (kt + 1) * 64;
            #pragma unroll
            for (int k = 0; k < 4; ++k)
                gl_lds16(a1 + (long)k * 64 * K, &lds[e * 16384 + sL + 4096 * k]);
            #pragma unroll
            for (int k = 0; k < BNF; ++k)
                gl_lds16(b1 + (long)k * 64 * K, &lds[32768 + e * 4096 * BNF + sL + 4096 * k]);
            if constexpr (BNF == 3) asm volatile("s_waitcnt vmcnt(7)" ::: "memory");
            else                    asm volatile("s_waitcnt vmcnt(8)" ::: "memory");
        } else {
            asm volatile("s_waitcnt vmcnt(0)" ::: "memory");
        }
        __builtin_amdgcn_sched_barrier(0);
        __builtin_amdgcn_s_barrier();          // (a) tile kt visible to all waves
        __builtin_amdgcn_sched_barrier(0);

        // ---- phase 0: B fragments (reused all phases) + A quadrant 0 ----
        bf16x8 bfr[BNF][2];
        #pragma unroll
        for (int nf = 0; nf < BNF; ++nf) {
            bfr[nf][0] = *(const bf16x8*)&lds[dB + boff0 + nf * 1024];
            bfr[nf][1] = *(const bf16x8*)&lds[dB + boff1 + nf * 1024];
        }
        {
            bf16x8 af[2][2];
            #pragma unroll
            for (int mm = 0; mm < 2; ++mm) {
                af[mm][0] = *(const bf16x8*)&lds[dA + aoff0 + mm * 1024];
                af[mm][1] = *(const bf16x8*)&lds[dA + aoff1 + mm * 1024];
            }
            asm volatile("s_waitcnt lgkmcnt(0)" ::: "memory");
            __builtin_amdgcn_sched_barrier(0);
            __builtin_amdgcn_s_setprio(1);
            #pragma unroll
            for (int mm = 0; mm < 2; ++mm)
                #pragma unroll
                for (int nf = 0; nf < BNF; ++nf) {
                    acc[mm][nf] = mfma16(af[mm][0], bfr[nf][0], acc[mm][nf]);
                    acc[mm][nf] = mfma16(af[mm][1], bfr[nf][1], acc[mm][nf]);
                }
            __builtin_amdgcn_s_setprio(0);
            __builtin_amdgcn_sched_barrier(0);
        }
        // ---- phases 1..3: ds_read issued pre-barrier, wait+MFMA post-barrier ----
        #pragma unroll
        for (int q = 1; q < 4; ++q) {
            bf16x8 af[2][2];
            #pragma unroll
            for (int mm = 0; mm < 2; ++mm) {
                af[mm][0] = *(const bf16x8*)&lds[dA + aoff0 + (q * 2 + mm) * 1024];
                af[mm][1] = *(const bf16x8*)&lds[dA + aoff1 + (q * 2 + mm) * 1024];
            }
            __builtin_amdgcn_sched_barrier(0);
            __builtin_amdgcn_s_barrier();
            asm volatile("s_waitcnt lgkmcnt(0)" ::: "memory");
            __builtin_amdgcn_sched_barrier(0);
            __builtin_amdgcn_s_setprio(1);
            #pragma unroll
            for (int mm = 0; mm < 2; ++mm)
                #pragma unroll
                for (int nf = 0; nf < BNF; ++nf) {
                    acc[q * 2 + mm][nf] = mfma16(af[mm][0], bfr[nf][0], acc[q * 2 + mm][nf]);
                    acc[q * 2 + mm][nf] = mfma16(af[mm][1], bfr[nf][1], acc[q * 2 + mm][nf]);
                }
            __builtin_amdgcn_s_setprio(0);
            __builtin_amdgcn_sched_barrier(0);
        }
        __builtin_amdgcn_s_barrier();          // (b) all reads done before next stage
        __builtin_amdgcn_sched_barrier(0);
    }

    // epilogue: C/D layout col = lane&15, row = (lane>>4)*4 + reg
    #pragma unroll
    for (int mf = 0; mf < 8; ++mf)
        #pragma unroll
        for (int nf = 0; nf < BNF; ++nf) {
            long row = m0 + wm * 128 + mf * 16 + ((l >> 4) << 2);
            float* cp = C + row * N + n0 + wn * (16 * BNF) + nf * 16 + (l & 15);
            #pragma unroll
            for (int r = 0; r < 4; ++r) cp[(long)r * N] = acc[mf][nf][r];
        }
}

// ---------------- RoPE + scatter ----------------
__global__ void k_rope_scatter(const float* __restrict__ qkv, const float* __restrict__ cosb,
                               const float* __restrict__ sinb, u16* __restrict__ Qb,
                               u16* __restrict__ Kb, u16* __restrict__ Vt,
                               float* __restrict__ present)
{
    long idx = (long)blockIdx.x * 256 + threadIdx.x;
    int pair = (int)(idx & 63);
    int rem  = (int)(idx >> 6);
    int slot = rem % 48;
    int tok  = rem / 48;
    int b = tok >> 11, s = tok & 2047;

    const float* base = qkv + (long)tok * 6144 + slot * 128;
    float x1 = base[pair], x2 = base[pair + 64];

    if (slot < 40) {
        float c  = cosb[s * 128 + pair];
        float sn = sinb[s * 128 + pair];
        float y1 = x1 * c - x2 * sn;
        float y2 = x2 * c + x1 * sn;
        if (slot < 32) {
            const float sc = 0.0883883476483184f;  // 1/sqrt(128), folded into Q
            long qoff = (((long)b * 32 + slot) * 2048 + s) * 128 + pair;
            Qb[qoff]      = f2bf(y1 * sc);
            Qb[qoff + 64] = f2bf(y2 * sc);
        } else {
            int kvh = slot - 32;
            long koff = (((long)b * 8 + kvh) * 2048 + s) * 128 + pair;
            Kb[koff]      = f2bf(y1);
            Kb[koff + 64] = f2bf(y2);
            long poff = ((((long)b * 2 + 0) * 8 + kvh) * 4096 + s) * 128 + pair;
            present[poff]      = y1;
            present[poff + 64] = y2;
        }
    } else {
        int kvh = slot - 40;
        long poff = ((((long)b * 2 + 1) * 8 + kvh) * 4096 + s) * 128 + pair;
        present[poff]      = x1;
        present[poff + 64] = x2;
        long voff = (((long)b * 8 + kvh) * 128 + pair) * 2048 + s;
        Vt[voff]             = f2bf(x1);
        Vt[voff + 64 * 2048] = f2bf(x2);
    }
}

// ---------------- causal GQA flash attention ----------------
// Block: 128 q-rows of one (b,h); 4 waves x 32 rows. Key tiles of 64, LDS-staged.
// LDS = 32 KB: Ks (16 KB, re-used as the per-wave P tiles after QK^T) + Vs (16 KB).
// qt is XOR-remapped per (h,b) so co-resident blocks have complementary causal depth.
// NOTE: launch_bounds must stay (256,2) — (256,3) caps VGPR at ~84 and spills
// the o/s/qf register working set (~200 regs) to scratch: R5 showed FETCH
// 70->715 MB and 2x duration. VGPR=128 @ (256,2) + 32KB LDS = 4 blocks/CU.
__global__ void __launch_bounds__(256, 2)
k_attn(const u16* __restrict__ Qb, const u16* __restrict__ Kb,
       const u16* __restrict__ Vt, u16* __restrict__ attnB)
{
    __shared__ __align__(16) u16 Ks[64 * 128];   // [key][d] chunk16 swz; P alias after QK
    __shared__ __align__(16) u16 Vs[128 * 64];   // [d][key], chunk8 swz ^(row&7)
    const int l = threadIdx.x & 63;
    const int w = threadIdx.x >> 6;
    const int h = blockIdx.y, b = blockIdx.z;
    // work-balance: bijective qt remap so a CU's co-resident blocks mix depths
    const int qt = blockIdx.x ^ (((h >> 2) + 8 * b) & 15);
    const int kvh = h >> 2;
    const int q0 = qt * 128;
    u16* Psw = &Ks[w * 2048];                    // per-wave 32x64 P, aliases K tile

    const long qbase = (((long)b * 32 + h) * 2048 + q0 + w * 32) * 128;
    bf16x8 qf[2][4];
    #pragma unroll
    for (int mi = 0; mi < 2; ++mi)
        #pragma unroll
        for (int kk = 0; kk < 4; ++kk)
            qf[mi][kk] = *(const bf16x8*)(Qb + qbase + (long)(mi * 16 + (l & 15)) * 128
                                          + kk * 32 + ((l >> 4) << 3));

    f32x4 zero = {0.f, 0.f, 0.f, 0.f};
    f32x4 o[2][8];
    float mst[2][4], lst[2][4];
    #pragma unroll
    for (int mi = 0; mi < 2; ++mi) {
        #pragma unroll
        for (int j = 0; j < 8; ++j) o[mi][j] = zero;
        #pragma unroll
        for (int r = 0; r < 4; ++r) { mst[mi][r] = -3.0e38f; lst[mi][r] = 0.f; }
    }

    const long kbase = ((long)b * 8 + kvh) * (2048L * 128);
    const long vbase = ((long)b * 8 + kvh) * (128L * 2048);

    const int nkt = (q0 >> 6) + 2;  // keys 0 .. q0+127
    for (int kt = 0; kt < nkt; ++kt) {
        const int k0 = kt * 64;
        __syncthreads();  // all waves done with previous tile's Ks(P alias) + Vs
        #pragma unroll
        for (int i = 0; i < 4; ++i) {     // K tile: 16KB, 4 chunks/wave
            int c = w * 4 + i;
            int row = c * 4 + (l >> 4);
            int lg = ((l & 15) ^ (row & 15)) << 3;
            gl_lds16(Kb + kbase + (long)(k0 + row) * 128 + lg, &Ks[c * 512]);
        }
        #pragma unroll
        for (int i = 0; i < 4; ++i) {     // V^T tile: 16KB
            int c = w * 4 + i;
            int row = c * 8 + (l >> 3);
            int lg = ((l & 7) ^ (row & 7)) << 3;
            gl_lds16(Vt + vbase + (long)row * 2048 + k0 + lg, &Vs[c * 512]);
        }
        __syncthreads();  // staging complete

        // ---- S = Q K^T (16x16x32 MFMA, reduce over D=128) ----
        f32x4 s[2][4];
        #pragma unroll
        for (int mi = 0; mi < 2; ++mi)
            #pragma unroll
            for (int nf = 0; nf < 4; ++nf) s[mi][nf] = zero;
        #pragma unroll
        for (int kk = 0; kk < 4; ++kk) {
            bf16x8 kf[4];
            #pragma unroll
            for (int nf = 0; nf < 4; ++nf) {
                int row = nf * 16 + (l & 15);
                int ph = (kk * 4 + (l >> 4)) ^ (row & 15);
                kf[nf] = *(const bf16x8*)&Ks[row * 128 + ph * 8];
            }
            #pragma unroll
            for (int mi = 0; mi < 2; ++mi)
                #pragma unroll
                for (int nf = 0; nf < 4; ++nf)
                    s[mi][nf] = mfma16(qf[mi][kk], kf[nf], s[mi][nf]);
        }
        // ---- causal mask ----
        #pragma unroll
        for (int mi = 0; mi < 2; ++mi)
            #pragma unroll
            for (int nf = 0; nf < 4; ++nf)
                #pragma unroll
                for (int r = 0; r < 4; ++r) {
                    int rowg = q0 + w * 32 + mi * 16 + ((l >> 4) << 2) + r;
                    int colg = k0 + nf * 16 + (l & 15);
                    if (colg > rowg) s[mi][nf][r] = -1.0e30f;
                }
        // ---- online softmax (row reduce over 16-lane group) ----
        #pragma unroll
        for (int mi = 0; mi < 2; ++mi)
            #pragma unroll
            for (int r = 0; r < 4; ++r) {
                float t = fmaxf(fmaxf(s[mi][0][r], s[mi][1][r]),
                                fmaxf(s[mi][2][r], s[mi][3][r]));
                t = fmaxf(t, __shfl_xor(t, 1));
                t = fmaxf(t, __shfl_xor(t, 2));
                t = fmaxf(t, __shfl_xor(t, 4));
                t = fmaxf(t, __shfl_xor(t, 8));
                float nm = fmaxf(mst[mi][r], t);
                float sc = __expf(mst[mi][r] - nm);
                mst[mi][r] = nm;
                lst[mi][r] *= sc;
                #pragma unroll
                for (int nf2 = 0; nf2 < 8; ++nf2) o[mi][nf2][r] *= sc;
            }
        __syncthreads();  // all waves done READING Ks before P overwrites it
        // ---- P = exp(S - m) -> bf16 -> per-wave LDS (aliases Ks, swizzled) ----
        #pragma unroll
        for (int mi = 0; mi < 2; ++mi)
            #pragma unroll
            for (int nf = 0; nf < 4; ++nf)
                #pragma unroll
                for (int r = 0; r < 4; ++r) {
                    float p = __expf(s[mi][nf][r] - mst[mi][r]);
                    lst[mi][r] += p;
                    int row = mi * 16 + ((l >> 4) << 2) + r;
                    int col = nf * 16 + (l & 15);
                    Psw[row * 64 + (((col >> 3) ^ (row & 7)) << 3) + (col & 7)] = f2bf(p);
                }
        // ---- O += P V  (same-wave LDS write->read, lgkmcnt-ordered) ----
        #pragma unroll
        for (int kk2 = 0; kk2 < 2; ++kk2) {
            bf16x8 pa[2];
            #pragma unroll
            for (int mi = 0; mi < 2; ++mi) {
                int row = mi * 16 + (l & 15);
                int ph = (kk2 * 4 + (l >> 4)) ^ (row & 7);
                pa[mi] = *(const bf16x8*)&Psw[row * 64 + ph * 8];
            }
            #pragma unroll
            for (int nf2 = 0; nf2 < 8; ++nf2) {
                int vrow = nf2 * 16 + (l & 15);
                int ph = (kk2 * 4 + (l >> 4)) ^ (vrow & 7);
                bf16x8 vf = *(const bf16x8*)&Vs[vrow * 64 + ph * 8];
                #pragma unroll
                for (int mi = 0; mi < 2; ++mi)
                    o[mi][nf2] = mfma16(pa[mi], vf, o[mi][nf2]);
            }
        }
    }

    // ---- finalize: reduce row-sums, normalize, store bf16 ----
    #pragma unroll
    for (int mi = 0; mi < 2; ++mi)
        #pragma unroll
        for (int r = 0; r < 4; ++r) {
            float t = lst[mi][r];
            t += __shfl_xor(t, 1);
            t += __shfl_xor(t, 2);
            t += __shfl_xor(t, 4);
            t += __shfl_xor(t, 8);
            lst[mi][r] = 1.0f / t;
        }
    #pragma unroll
    for (int mi = 0; mi < 2; ++mi)
        #pragma unroll
        for (int nf2 = 0; nf2 < 8; ++nf2)
            #pragma unroll
            for (int r = 0; r < 4; ++r) {
                long row = (long)b * 2048 + q0 + w * 32 + mi * 16 + ((l >> 4) << 2) + r;
                attnB[row * 4096 + h * 128 + nf2 * 16 + (l & 15)] =
                    f2bf(o[mi][nf2][r] * lst[mi][r]);
            }
}

extern "C" void kernel_launch(void* const* d_in, const int* in_sizes, int n_in,
                              void* d_out, int out_size, void* d_ws, size_t ws_size,
                              hipStream_t stream)
{
    (void)in_sizes; (void)n_in; (void)out_size; (void)ws_size;
    const float* hidden = (const float*)d_in[0];
    const float* past   = (const float*)d_in[1];
    const float* cosb   = (const float*)d_in[2];
    const float* sinb   = (const float*)d_in[3];
    const float* Wq     = (const float*)d_in[4];
    const float* Wk     = (const float*)d_in[5];
    const float* Wv     = (const float*)d_in[6];
    const float* Wo     = (const float*)d_in[7];
    float* out     = (float*)d_out;             // (B,S,HID) f32
    float* present = out + 16777216L;           // (B,2,KVH,MAXPOS,D) f32

    // workspace layout (total 224 MB)
    char* ws = (char*)d_ws;
    u16*  hiddenB = (u16*)(ws);                  // 33,554,432 B (later aliased as Qbuf)
    u16*  WqkvT   = (u16*)(ws + 33554432L);      // 50,331,648 B  (6144 x 4096 bf16)
    u16*  WoT     = (u16*)(ws + 83886080L);      // 33,554,432 B
    float* QKVf   = (float*)(ws + 117440512L);   // 100,663,296 B (later aliased as attnB)
    u16*  Kb      = (u16*)(ws + 218103808L);     // 8,388,608 B
    u16*  Vt      = (u16*)(ws + 226492416L);     // 8,388,608 B
    u16*  Qbuf    = hiddenB;                     // reuse after QKV GEMM consumed hiddenB
    u16*  attnB   = (u16*)QKVf;                  // reuse after rope consumed QKVf

    static bool attr_done = false;
    if (!attr_done) {
        hipFuncSetAttribute((const void*)k_gemm8<3>,
                            hipFuncAttributeMaxDynamicSharedMemorySize, 114688);
        hipFuncSetAttribute((const void*)k_gemm8<4>,
                            hipFuncAttributeMaxDynamicSharedMemorySize, 131072);
        attr_done = true;
    }

    k_cast_bf16<<<16384, 256, 0, stream>>>(hidden, hiddenB);
    dim3 tb(32, 8);
    k_transpose_cvt<<<dim3(128, 128), tb, 0, stream>>>(Wq, WqkvT, 4096, 4096);
    k_transpose_cvt<<<dim3(32, 128),  tb, 0, stream>>>(Wk, WqkvT + 4096L * 4096, 4096, 1024);
    k_transpose_cvt<<<dim3(32, 128),  tb, 0, stream>>>(Wv, WqkvT + 5120L * 4096, 4096, 1024);
    k_transpose_cvt<<<dim3(128, 128), tb, 0, stream>>>(Wo, WoT, 4096, 4096);
    k_copy_half<<<8192, 256, 0, stream>>>((const float4*)past, (float4*)present);
    // QKV: M=4096, N=6144, tiles 256x192 -> grid 16x32 = 512 (2.0 CU-rounds)
    k_gemm8<3><<<512, 512, 114688, stream>>>(hiddenB, WqkvT, QKVf, 4096, 6144, 4096, 32);
    k_rope_scatter<<<49152, 256, 0, stream>>>(QKVf, cosb, sinb, Qbuf, Kb, Vt, present);
    k_attn<<<dim3(16, 32, 2), 256, 0, stream>>>(Qbuf, Kb, Vt, attnB);
    // Wo: M=N=4096, tiles 256x256 -> grid 16x16 = 256 (1.0 CU-rounds)
    k_gemm8<4><<<256, 512, 131072, stream>>>(attnB, WoT, out, 4096, 4096, 4096, 16);
}

// Round 8
// 600.618 us; speedup vs baseline: 1.6471x; 1.1527x over previous
//
#include <hip/hip_runtime.h>
#include <hip/hip_bf16.h>

typedef unsigned short u16;
typedef __bf16 bf16x8 __attribute__((ext_vector_type(8)));
typedef float  f32x4  __attribute__((ext_vector_type(4)));

__device__ __forceinline__ u16 f2bf(float f) {
    return __builtin_bit_cast(u16, (__bf16)f);
}
__device__ __forceinline__ f32x4 mfma16(bf16x8 a, bf16x8 b, f32x4 c) {
    return __builtin_amdgcn_mfma_f32_16x16x32_bf16(a, b, c, 0, 0, 0);
}
// async global->LDS, 16B per lane; LDS dest is wave-uniform base + lane*16
__device__ __forceinline__ void gl_lds16(const void* g, void* l) {
    __builtin_amdgcn_global_load_lds((const __attribute__((address_space(1))) void*)g,
                                     (__attribute__((address_space(3))) void*)l, 16, 0, 0);
}

// ---------------- elementwise f32 -> bf16 (4 elems/thread, exact grid) ----------------
__global__ void k_cast_bf16(const float* __restrict__ src, u16* __restrict__ dst) {
    long i = ((long)blockIdx.x * blockDim.x + threadIdx.x) * 4;
    float4 v = *(const float4*)(src + i);
    ushort4 o;
    o.x = f2bf(v.x); o.y = f2bf(v.y); o.z = f2bf(v.z); o.w = f2bf(v.w);
    *(ushort4*)(dst + i) = o;
}

// ---------------- f32 (K x N) -> bf16 transposed (N x K) ----------------
__global__ void k_transpose_cvt(const float* __restrict__ src, u16* __restrict__ dst,
                                int K, int N) {
    __shared__ float t[32][33];
    int n0 = blockIdx.x * 32, k0 = blockIdx.y * 32;
    int tx = threadIdx.x, ty = threadIdx.y;
    #pragma unroll
    for (int i = 0; i < 32; i += 8)
        t[ty + i][tx] = src[(long)(k0 + ty + i) * N + n0 + tx];
    __syncthreads();
    #pragma unroll
    for (int i = 0; i < 32; i += 8)
        dst[(long)(n0 + ty + i) * K + k0 + tx] = f2bf(t[tx][ty + i]);
}

// ---------------- copy only rows s in [2048,4096) of past -> present ----------------
__global__ void k_copy_half(const float4* __restrict__ src, float4* __restrict__ dst) {
    long i = (long)blockIdx.x * 256 + threadIdx.x;   // 0 .. 2^21-1
    long g = i >> 16;                                // plane index (32 planes)
    long inner = i & 65535;
    long off = g * 131072 + 65536 + inner;
    dst[off] = src[off];
}

// ================= 256-tile counted-vmcnt GEMM, 4-phase interleave =================
// (structure proven R6/R7; see comments there)
template<int BNF>
__global__ void __launch_bounds__(512, 2)
k_gemm8(const u16* __restrict__ A, const u16* __restrict__ Bt,
        float* __restrict__ C, int M, int N, int K, int gx)
{
    extern __shared__ u16 lds[];
    const int nwg = gridDim.x;
    const int bid = blockIdx.x;
    const int swzb = (bid & 7) * (nwg >> 3) + (bid >> 3);
    const long m0 = (long)(swzb / gx) * 256;
    const long n0 = (long)(swzb % gx) * (64 * BNF);

    const int t = threadIdx.x;
    const int l = t & 63;
    const int w = t >> 6;
    const int wm = w >> 2, wn = w & 3;

    const int srow = t >> 3;
    const int scol = ((t & 7) ^ (srow & 7)) << 3;      // u16 col within 64-col tile row
    const u16* ap = A  + (m0 + srow) * (long)K + scol;
    const u16* bp = Bt + (n0 + srow) * (long)K + scol;
    const int sL = t * 8;                               // lds u16 offset (+4096 per k)

    const int swz0 = (((l >> 4) ^ (l & 7)) << 3);       // k-slice 0
    const int swz1 = ((((l >> 4) | 4) ^ (l & 7)) << 3); // k-slice 1
    const int arow = wm * 128 + (l & 15);
    const int aoff0 = arow * 64 + swz0, aoff1 = arow * 64 + swz1;
    const int brow = wn * (16 * BNF) + (l & 15);
    const int boff0 = brow * 64 + swz0, boff1 = brow * 64 + swz1;

    f32x4 acc[8][BNF];
    #pragma unroll
    for (int i = 0; i < 8; ++i)
        #pragma unroll
        for (int j = 0; j < BNF; ++j) acc[i][j] = (f32x4){0.f, 0.f, 0.f, 0.f};

    const int nt = K >> 6;
    #pragma unroll
    for (int k = 0; k < 4; ++k)
        gl_lds16(ap + (long)k * 64 * K, &lds[sL + 4096 * k]);
    #pragma unroll
    for (int k = 0; k < BNF; ++k)
        gl_lds16(bp + (long)k * 64 * K, &lds[32768 + sL + 4096 * k]);

    for (int kt = 0; kt < nt; ++kt) {
        const int d = kt & 1;
        const int dA = d * 16384, dB = 32768 + d * 4096 * BNF;
        if (kt + 1 < nt) {
            const int e = d ^ 1;
            const u16* a1 = ap + (kt + 1) * 64;
            const u16* b1 = bp + (kt + 1) * 64;
            #pragma unroll
            for (int k = 0; k < 4; ++k)
                gl_lds16(a1 + (long)k * 64 * K, &lds[e * 16384 + sL + 4096 * k]);
            #pragma unroll
            for (int k = 0; k < BNF; ++k)
                gl_lds16(b1 + (long)k * 64 * K, &lds[32768 + e * 4096 * BNF + sL + 4096 * k]);
            if constexpr (BNF == 3) asm volatile("s_waitcnt vmcnt(7)" ::: "memory");
            else                    asm volatile("s_waitcnt vmcnt(8)" ::: "memory");
        } else {
            asm volatile("s_waitcnt vmcnt(0)" ::: "memory");
        }
        __builtin_amdgcn_sched_barrier(0);
        __builtin_amdgcn_s_barrier();          // (a) tile kt visible to all waves
        __builtin_amdgcn_sched_barrier(0);

        bf16x8 bfr[BNF][2];
        #pragma unroll
        for (int nf = 0; nf < BNF; ++nf) {
            bfr[nf][0] = *(const bf16x8*)&lds[dB + boff0 + nf * 1024];
            bfr[nf][1] = *(const bf16x8*)&lds[dB + boff1 + nf * 1024];
        }
        {
            bf16x8 af[2][2];
            #pragma unroll
            for (int mm = 0; mm < 2; ++mm) {
                af[mm][0] = *(const bf16x8*)&lds[dA + aoff0 + mm * 1024];
                af[mm][1] = *(const bf16x8*)&lds[dA + aoff1 + mm * 1024];
            }
            asm volatile("s_waitcnt lgkmcnt(0)" ::: "memory");
            __builtin_amdgcn_sched_barrier(0);
            __builtin_amdgcn_s_setprio(1);
            #pragma unroll
            for (int mm = 0; mm < 2; ++mm)
                #pragma unroll
                for (int nf = 0; nf < BNF; ++nf) {
                    acc[mm][nf] = mfma16(af[mm][0], bfr[nf][0], acc[mm][nf]);
                    acc[mm][nf] = mfma16(af[mm][1], bfr[nf][1], acc[mm][nf]);
                }
            __builtin_amdgcn_s_setprio(0);
            __builtin_amdgcn_sched_barrier(0);
        }
        #pragma unroll
        for (int q = 1; q < 4; ++q) {
            bf16x8 af[2][2];
            #pragma unroll
            for (int mm = 0; mm < 2; ++mm) {
                af[mm][0] = *(const bf16x8*)&lds[dA + aoff0 + (q * 2 + mm) * 1024];
                af[mm][1] = *(const bf16x8*)&lds[dA + aoff1 + (q * 2 + mm) * 1024];
            }
            __builtin_amdgcn_sched_barrier(0);
            __builtin_amdgcn_s_barrier();
            asm volatile("s_waitcnt lgkmcnt(0)" ::: "memory");
            __builtin_amdgcn_sched_barrier(0);
            __builtin_amdgcn_s_setprio(1);
            #pragma unroll
            for (int mm = 0; mm < 2; ++mm)
                #pragma unroll
                for (int nf = 0; nf < BNF; ++nf) {
                    acc[q * 2 + mm][nf] = mfma16(af[mm][0], bfr[nf][0], acc[q * 2 + mm][nf]);
                    acc[q * 2 + mm][nf] = mfma16(af[mm][1], bfr[nf][1], acc[q * 2 + mm][nf]);
                }
            __builtin_amdgcn_s_setprio(0);
            __builtin_amdgcn_sched_barrier(0);
        }
        __builtin_amdgcn_s_barrier();          // (b) all reads done before next stage
        __builtin_amdgcn_sched_barrier(0);
    }

    #pragma unroll
    for (int mf = 0; mf < 8; ++mf)
        #pragma unroll
        for (int nf = 0; nf < BNF; ++nf) {
            long row = m0 + wm * 128 + mf * 16 + ((l >> 4) << 2);
            float* cp = C + row * N + n0 + wn * (16 * BNF) + nf * 16 + (l & 15);
            #pragma unroll
            for (int r = 0; r < 4; ++r) cp[(long)r * N] = acc[mf][nf][r];
        }
}

// ---------------- RoPE + scatter ----------------
__global__ void k_rope_scatter(const float* __restrict__ qkv, const float* __restrict__ cosb,
                               const float* __restrict__ sinb, u16* __restrict__ Qb,
                               u16* __restrict__ Kb, u16* __restrict__ Vt,
                               float* __restrict__ present)
{
    long idx = (long)blockIdx.x * 256 + threadIdx.x;
    int pair = (int)(idx & 63);
    int rem  = (int)(idx >> 6);
    int slot = rem % 48;
    int tok  = rem / 48;
    int b = tok >> 11, s = tok & 2047;

    const float* base = qkv + (long)tok * 6144 + slot * 128;
    float x1 = base[pair], x2 = base[pair + 64];

    if (slot < 40) {
        float c  = cosb[s * 128 + pair];
        float sn = sinb[s * 128 + pair];
        float y1 = x1 * c - x2 * sn;
        float y2 = x2 * c + x1 * sn;
        if (slot < 32) {
            const float sc = 0.0883883476483184f;  // 1/sqrt(128), folded into Q
            long qoff = (((long)b * 32 + slot) * 2048 + s) * 128 + pair;
            Qb[qoff]      = f2bf(y1 * sc);
            Qb[qoff + 64] = f2bf(y2 * sc);
        } else {
            int kvh = slot - 32;
            long koff = (((long)b * 8 + kvh) * 2048 + s) * 128 + pair;
            Kb[koff]      = f2bf(y1);
            Kb[koff + 64] = f2bf(y2);
            long poff = ((((long)b * 2 + 0) * 8 + kvh) * 4096 + s) * 128 + pair;
            present[poff]      = y1;
            present[poff + 64] = y2;
        }
    } else {
        int kvh = slot - 40;
        long poff = ((((long)b * 2 + 1) * 8 + kvh) * 4096 + s) * 128 + pair;
        present[poff]      = x1;
        present[poff + 64] = x2;
        long voff = (((long)b * 8 + kvh) * 128 + pair) * 2048 + s;
        Vt[voff]             = f2bf(x1);
        Vt[voff + 64 * 2048] = f2bf(x2);
    }
}

// ---------------- causal GQA flash attention (uniform-work paired q-tiles) ----------------
// Block p in [0,8) processes q-tiles qt=p and qt=15-p of one (b,h): combined
// causal work = (2p+2)+(2(15-p)+2) = 34 K-tile-steps for EVERY block -> no
// straggler tail. Grid 8x32x2 = 512 uniform blocks, all co-resident (2/CU).
// 4 waves x 32 q-rows. LDS 32KB: Ks (16KB; P aliases it after QK^T) + Vs (16KB).
// launch_bounds must stay (256,2): (256,3) caps VGPR ~84 and spills (R5).
__global__ void __launch_bounds__(256, 2)
k_attn(const u16* __restrict__ Qb, const u16* __restrict__ Kb,
       const u16* __restrict__ Vt, u16* __restrict__ attnB)
{
    __shared__ __align__(16) u16 Ks[64 * 128];   // [key][d] chunk16 swz; P alias after QK
    __shared__ __align__(16) u16 Vs[128 * 64];   // [d][key], chunk8 swz ^(row&7)
    const int l = threadIdx.x & 63;
    const int w = threadIdx.x >> 6;
    const int h = blockIdx.y, b = blockIdx.z;
    const int p = blockIdx.x;
    const int kvh = h >> 2;
    u16* Psw = &Ks[w * 2048];                    // per-wave 32x64 P, aliases K tile

    const long kbase = ((long)b * 8 + kvh) * (2048L * 128);
    const long vbase = ((long)b * 8 + kvh) * (128L * 2048);
    f32x4 zero = {0.f, 0.f, 0.f, 0.f};

    for (int half = 0; half < 2; ++half) {
        const int qt = half ? (15 - p) : p;
        const int q0 = qt * 128;

        const long qbase = (((long)b * 32 + h) * 2048 + q0 + w * 32) * 128;
        bf16x8 qf[2][4];
        #pragma unroll
        for (int mi = 0; mi < 2; ++mi)
            #pragma unroll
            for (int kk = 0; kk < 4; ++kk)
                qf[mi][kk] = *(const bf16x8*)(Qb + qbase + (long)(mi * 16 + (l & 15)) * 128
                                              + kk * 32 + ((l >> 4) << 3));

        f32x4 o[2][8];
        float mst[2][4], lst[2][4];
        #pragma unroll
        for (int mi = 0; mi < 2; ++mi) {
            #pragma unroll
            for (int j = 0; j < 8; ++j) o[mi][j] = zero;
            #pragma unroll
            for (int r = 0; r < 4; ++r) { mst[mi][r] = -3.0e38f; lst[mi][r] = 0.f; }
        }

        const int nkt = (q0 >> 6) + 2;  // keys 0 .. q0+127
        for (int kt = 0; kt < nkt; ++kt) {
            const int k0 = kt * 64;
            __syncthreads();  // all waves done with previous tile's Ks(P alias) + Vs
            #pragma unroll
            for (int i = 0; i < 4; ++i) {     // K tile: 16KB, 4 chunks/wave
                int c = w * 4 + i;
                int row = c * 4 + (l >> 4);
                int lg = ((l & 15) ^ (row & 15)) << 3;
                gl_lds16(Kb + kbase + (long)(k0 + row) * 128 + lg, &Ks[c * 512]);
            }
            #pragma unroll
            for (int i = 0; i < 4; ++i) {     // V^T tile: 16KB
                int c = w * 4 + i;
                int row = c * 8 + (l >> 3);
                int lg = ((l & 7) ^ (row & 7)) << 3;
                gl_lds16(Vt + vbase + (long)row * 2048 + k0 + lg, &Vs[c * 512]);
            }
            __syncthreads();  // staging complete

            // ---- S = Q K^T ----
            f32x4 s[2][4];
            #pragma unroll
            for (int mi = 0; mi < 2; ++mi)
                #pragma unroll
                for (int nf = 0; nf < 4; ++nf) s[mi][nf] = zero;
            #pragma unroll
            for (int kk = 0; kk < 4; ++kk) {
                bf16x8 kf[4];
                #pragma unroll
                for (int nf = 0; nf < 4; ++nf) {
                    int row = nf * 16 + (l & 15);
                    int ph = (kk * 4 + (l >> 4)) ^ (row & 15);
                    kf[nf] = *(const bf16x8*)&Ks[row * 128 + ph * 8];
                }
                #pragma unroll
                for (int mi = 0; mi < 2; ++mi)
                    #pragma unroll
                    for (int nf = 0; nf < 4; ++nf)
                        s[mi][nf] = mfma16(qf[mi][kk], kf[nf], s[mi][nf]);
            }
            // ---- causal mask ----
            #pragma unroll
            for (int mi = 0; mi < 2; ++mi)
                #pragma unroll
                for (int nf = 0; nf < 4; ++nf)
                    #pragma unroll
                    for (int r = 0; r < 4; ++r) {
                        int rowg = q0 + w * 32 + mi * 16 + ((l >> 4) << 2) + r;
                        int colg = k0 + nf * 16 + (l & 15);
                        if (colg > rowg) s[mi][nf][r] = -1.0e30f;
                    }
            // ---- online softmax (row reduce over 16-lane group) ----
            #pragma unroll
            for (int mi = 0; mi < 2; ++mi)
                #pragma unroll
                for (int r = 0; r < 4; ++r) {
                    float t = fmaxf(fmaxf(s[mi][0][r], s[mi][1][r]),
                                    fmaxf(s[mi][2][r], s[mi][3][r]));
                    t = fmaxf(t, __shfl_xor(t, 1));
                    t = fmaxf(t, __shfl_xor(t, 2));
                    t = fmaxf(t, __shfl_xor(t, 4));
                    t = fmaxf(t, __shfl_xor(t, 8));
                    float nm = fmaxf(mst[mi][r], t);
                    float sc = __expf(mst[mi][r] - nm);
                    mst[mi][r] = nm;
                    lst[mi][r] *= sc;
                    #pragma unroll
                    for (int nf2 = 0; nf2 < 8; ++nf2) o[mi][nf2][r] *= sc;
                }
            __syncthreads();  // all waves done READING Ks before P overwrites it
            // ---- P = exp(S - m) -> bf16 -> per-wave LDS (aliases Ks) ----
            #pragma unroll
            for (int mi = 0; mi < 2; ++mi)
                #pragma unroll
                for (int nf = 0; nf < 4; ++nf)
                    #pragma unroll
                    for (int r = 0; r < 4; ++r) {
                        float pv = __expf(s[mi][nf][r] - mst[mi][r]);
                        lst[mi][r] += pv;
                        int row = mi * 16 + ((l >> 4) << 2) + r;
                        int col = nf * 16 + (l & 15);
                        Psw[row * 64 + (((col >> 3) ^ (row & 7)) << 3) + (col & 7)] = f2bf(pv);
                    }
            // ---- O += P V ----
            #pragma unroll
            for (int kk2 = 0; kk2 < 2; ++kk2) {
                bf16x8 pa[2];
                #pragma unroll
                for (int mi = 0; mi < 2; ++mi) {
                    int row = mi * 16 + (l & 15);
                    int ph = (kk2 * 4 + (l >> 4)) ^ (row & 7);
                    pa[mi] = *(const bf16x8*)&Psw[row * 64 + ph * 8];
                }
                #pragma unroll
                for (int nf2 = 0; nf2 < 8; ++nf2) {
                    int vrow = nf2 * 16 + (l & 15);
                    int ph = (kk2 * 4 + (l >> 4)) ^ (vrow & 7);
                    bf16x8 vf = *(const bf16x8*)&Vs[vrow * 64 + ph * 8];
                    #pragma unroll
                    for (int mi = 0; mi < 2; ++mi)
                        o[mi][nf2] = mfma16(pa[mi], vf, o[mi][nf2]);
                }
            }
        }

        // ---- finalize this q-tile ----
        #pragma unroll
        for (int mi = 0; mi < 2; ++mi)
            #pragma unroll
            for (int r = 0; r < 4; ++r) {
                float t = lst[mi][r];
                t += __shfl_xor(t, 1);
                t += __shfl_xor(t, 2);
                t += __shfl_xor(t, 4);
                t += __shfl_xor(t, 8);
                lst[mi][r] = 1.0f / t;
            }
        #pragma unroll
        for (int mi = 0; mi < 2; ++mi)
            #pragma unroll
            for (int nf2 = 0; nf2 < 8; ++nf2)
                #pragma unroll
                for (int r = 0; r < 4; ++r) {
                    long row = (long)b * 2048 + q0 + w * 32 + mi * 16 + ((l >> 4) << 2) + r;
                    attnB[row * 4096 + h * 128 + nf2 * 16 + (l & 15)] =
                        f2bf(o[mi][nf2][r] * lst[mi][r]);
                }
    }
}

extern "C" void kernel_launch(void* const* d_in, const int* in_sizes, int n_in,
                              void* d_out, int out_size, void* d_ws, size_t ws_size,
                              hipStream_t stream)
{
    (void)in_sizes; (void)n_in; (void)out_size; (void)ws_size;
    const float* hidden = (const float*)d_in[0];
    const float* past   = (const float*)d_in[1];
    const float* cosb   = (const float*)d_in[2];
    const float* sinb   = (const float*)d_in[3];
    const float* Wq     = (const float*)d_in[4];
    const float* Wk     = (const float*)d_in[5];
    const float* Wv     = (const float*)d_in[6];
    const float* Wo     = (const float*)d_in[7];
    float* out     = (float*)d_out;             // (B,S,HID) f32
    float* present = out + 16777216L;           // (B,2,KVH,MAXPOS,D) f32

    // workspace layout (total 224 MB)
    char* ws = (char*)d_ws;
    u16*  hiddenB = (u16*)(ws);                  // 33,554,432 B (later aliased as Qbuf)
    u16*  WqkvT   = (u16*)(ws + 33554432L);      // 50,331,648 B  (6144 x 4096 bf16)
    u16*  WoT     = (u16*)(ws + 83886080L);      // 33,554,432 B
    float* QKVf   = (float*)(ws + 117440512L);   // 100,663,296 B (later aliased as attnB)
    u16*  Kb      = (u16*)(ws + 218103808L);     // 8,388,608 B
    u16*  Vt      = (u16*)(ws + 226492416L);     // 8,388,608 B
    u16*  Qbuf    = hiddenB;                     // reuse after QKV GEMM consumed hiddenB
    u16*  attnB   = (u16*)QKVf;                  // reuse after rope consumed QKVf

    static bool attr_done = false;
    if (!attr_done) {
        hipFuncSetAttribute((const void*)k_gemm8<3>,
                            hipFuncAttributeMaxDynamicSharedMemorySize, 114688);
        hipFuncSetAttribute((const void*)k_gemm8<4>,
                            hipFuncAttributeMaxDynamicSharedMemorySize, 131072);
        attr_done = true;
    }

    k_cast_bf16<<<16384, 256, 0, stream>>>(hidden, hiddenB);
    dim3 tb(32, 8);
    k_transpose_cvt<<<dim3(128, 128), tb, 0, stream>>>(Wq, WqkvT, 4096, 4096);
    k_transpose_cvt<<<dim3(32, 128),  tb, 0, stream>>>(Wk, WqkvT + 4096L * 4096, 4096, 1024);
    k_transpose_cvt<<<dim3(32, 128),  tb, 0, stream>>>(Wv, WqkvT + 5120L * 4096, 4096, 1024);
    k_transpose_cvt<<<dim3(128, 128), tb, 0, stream>>>(Wo, WoT, 4096, 4096);
    k_copy_half<<<8192, 256, 0, stream>>>((const float4*)past, (float4*)present);
    // QKV: M=4096, N=6144, tiles 256x192 -> grid 16x32 = 512 (2.0 CU-rounds)
    k_gemm8<3><<<512, 512, 114688, stream>>>(hiddenB, WqkvT, QKVf, 4096, 6144, 4096, 32);
    k_rope_scatter<<<49152, 256, 0, stream>>>(QKVf, cosb, sinb, Qbuf, Kb, Vt, present);
    // attn: paired q-tiles (p, 15-p) -> uniform 34 K-steps/block, 512 blocks
    k_attn<<<dim3(8, 32, 2), 256, 0, stream>>>(Qbuf, Kb, Vt, attnB);
    // Wo: M=N=4096, tiles 256x256 -> grid 16x16 = 256 (1.0 CU-rounds)
    k_gemm8<4><<<256, 512, 131072, stream>>>(attnB, WoT, out, 4096, 4096, 4096, 16);
}